// Round 1
// 108.096 us; speedup vs baseline: 1.0775x; 1.0775x over previous
//
#include <hip/hip_runtime.h>
#include <hip/hip_fp16.h>

// Problem constants (from reference)
#define SPP   16
#define SH    256
#define SW    256
#define HI    1024
#define WI    1024
#define CH    3
#define BATCH 4

#define TS    16    // sensor tile = 16x16 px per block
#define MAXD  88    // max bbox rows/cols at t=1: 84 px span +2 bilinear +2 safety
#define NTHR  512   // 2 threads per sensor px: lane pair splits the 16 spp 8/8

// tanh via v_exp_f32; |arg| <= ~1.2 here, abs error ~1e-6 (threshold 1.7e-2).
__device__ __forceinline__ float fast_tanh(float x) {
    const float e = __expf(2.0f * x);
    return (e - 1.0f) * __builtin_amdgcn_rcpf(e + 1.0f);
}

// Per-block: stage the warped-image bbox of a 16x16 sensor tile into LDS as
// planar fp16 (half2 RG + half B = 6 B/px -> 46.5 KB -> 3 blocks/CU), then
// lane pairs (spp 0..7 / 8..15) sample bilinearly from LDS and combine via
// one xor-1 shuffle. 24 waves/CU target (was 8) to hide gather latency.
__global__ __launch_bounds__(NTHR, 6) void foveated_tile(
    const float* __restrict__ img,
    const float* __restrict__ t_ptr,
    const float* __restrict__ jitter,
    float* __restrict__ out)
{
    __shared__ __half2 lds_rg[MAXD * MAXD];  // 30976 B
    __shared__ __half  lds_b [MAXD * MAXD];  // 15488 B

    // XCD slab swizzle: each XCD gets 128 contiguous logical blocks.
    const int bid  = blockIdx.x;
    const int L    = (bid & 7) * 128 + (bid >> 3);
    const int b    = L >> 8;
    const int trow = (L >> 4) & 15;
    const int tcol = L & 15;
    const int sx0  = tcol * TS;
    const int sy0  = trow * TS;

    const float step  = 2.0f / 256.0f;
    const float tt    = t_ptr[0];
    const float inv_s = __builtin_amdgcn_rcpf(fast_tanh(tt));

    // Uniform bbox of the tile's warped footprint (warp is monotone/separable).
    auto gmap = [&](float p) {
        float g = (fast_tanh(tt * p) * inv_s + 1.0f) * 512.0f - 0.5f;
        return fminf(fmaxf(g, 0.0f), 1023.0f);
    };
    const float pxmin = -1.0f + sx0 * step, pxmax = pxmin + TS * step;
    const float pymin = -1.0f + sy0 * step, pymax = pymin + TS * step;
    const int x_lo = max((int)gmap(pxmin) - 1, 0);
    const int x_hi = min((int)gmap(pxmax) + 2, WI - 1);
    const int y_lo = max((int)gmap(pymin) - 1, 0);
    const int y_hi = min((int)gmap(pymax) + 2, HI - 1);
    const int ncols = x_hi - x_lo + 1;
    const int nrows = y_hi - y_lo + 1;
    const bool fits = (ncols <= MAXD) && (nrows <= MAXD);  // always true at t=1

    const size_t plane = (size_t)HI * WI;
    const float* __restrict__ p0 = img + (size_t)(b * CH) * plane;
    const float* __restrict__ p1 = p0 + plane;
    const float* __restrict__ p2 = p1 + plane;

    const int th = threadIdx.x;
    const int h  = th & 1;    // spp half: 0 -> spp 0..7, 1 -> spp 8..15
    const int p  = th >> 1;   // pixel index within the tile
    const int sx = sx0 + (p & 15);
    const int sy = sy0 + (p >> 4);

    const float px = -1.0f + sx * step;
    const float py = -1.0f + sy * step;

    float acc0 = 0.0f, acc1 = 0.0f, acc2 = 0.0f, dsum = 0.0f;

    const float2* __restrict__ jit2 = (const float2*)jitter;
    const int jbase = h * 8 * (SH * SW) + sy * SW + sx;

    if (fits) {
        // ---- Stage bbox -> LDS (planar fp16), coalesced global reads ----
        const int npix = nrows * ncols;
        const unsigned mdiv = (1u << 22) / (unsigned)ncols + 1u;  // i<7744: exact
        for (int i = th; i < npix; i += NTHR) {
            const int r = (int)(((unsigned)i * mdiv) >> 22);
            const int c = i - r * ncols;
            const int g = (y_lo + r) * WI + (x_lo + c);
            lds_rg[r * MAXD + c] = __floats2half2_rn(p0[g], p1[g]);
            lds_b [r * MAXD + c] = __float2half_rn(p2[g]);
        }
        __syncthreads();

        // ---- Sample this lane's 8 spp from LDS ----
        #pragma unroll 2
        for (int k = 0; k < 8; ++k) {
            const float2 j = jit2[k * (SH * SW) + jbase];
            const float posx = px + j.x * step;
            const float posy = py + j.y * step;

            const float thx = fast_tanh(tt * posx);
            const float thy = fast_tanh(tt * posy);
            const float ddx = tt * (1.0f - thx * thx) * inv_s;
            const float ddy = tt * (1.0f - thy * thy) * inv_s;
            const float det = ddx * ddy;

            float gx = (thx * inv_s + 1.0f) * 512.0f - 0.5f;
            float gy = (thy * inv_s + 1.0f) * 512.0f - 0.5f;
            gx = fminf(fmaxf(gx, 0.0f), (float)(WI - 1));
            gy = fminf(fmaxf(gy, 0.0f), (float)(HI - 1));

            const int xb = min((int)gx, WI - 2);
            const int yb = min((int)gy, HI - 2);
            const float fx = gx - (float)xb;
            const float fy = gy - (float)yb;

            const float w00 = (1.0f - fx) * (1.0f - fy) * det;
            const float w01 = fx * (1.0f - fy) * det;
            const float w10 = (1.0f - fx) * fy * det;
            const float w11 = fx * fy * det;
            dsum += det;

            const int lidx = (yb - y_lo) * MAXD + (xb - x_lo);
            const float2 f00 = __half22float2(lds_rg[lidx]);
            const float2 f01 = __half22float2(lds_rg[lidx + 1]);
            const float2 f10 = __half22float2(lds_rg[lidx + MAXD]);
            const float2 f11 = __half22float2(lds_rg[lidx + MAXD + 1]);
            const float v00 = __half2float(lds_b[lidx]);
            const float v01 = __half2float(lds_b[lidx + 1]);
            const float v10 = __half2float(lds_b[lidx + MAXD]);
            const float v11 = __half2float(lds_b[lidx + MAXD + 1]);

            acc0 += w00 * f00.x + w01 * f01.x + w10 * f10.x + w11 * f11.x;
            acc1 += w00 * f00.y + w01 * f01.y + w10 * f10.y + w11 * f11.y;
            acc2 += w00 * v00   + w01 * v01   + w10 * v10   + w11 * v11;
        }
    } else {
        // ---- Fallback: direct global gathers (never taken at t=1) ----
        #pragma unroll 2
        for (int k = 0; k < 8; ++k) {
            const float2 j = jit2[k * (SH * SW) + jbase];
            const float posx = px + j.x * step;
            const float posy = py + j.y * step;

            const float thx = fast_tanh(tt * posx);
            const float thy = fast_tanh(tt * posy);
            const float ddx = tt * (1.0f - thx * thx) * inv_s;
            const float ddy = tt * (1.0f - thy * thy) * inv_s;
            const float det = ddx * ddy;

            float gx = (thx * inv_s + 1.0f) * 512.0f - 0.5f;
            float gy = (thy * inv_s + 1.0f) * 512.0f - 0.5f;
            gx = fminf(fmaxf(gx, 0.0f), (float)(WI - 1));
            gy = fminf(fmaxf(gy, 0.0f), (float)(HI - 1));

            const int xb = min((int)gx, WI - 2);
            const int yb = min((int)gy, HI - 2);
            const float fx = gx - (float)xb;
            const float fy = gy - (float)yb;

            const float w00 = (1.0f - fx) * (1.0f - fy) * det;
            const float w01 = fx * (1.0f - fy) * det;
            const float w10 = (1.0f - fx) * fy * det;
            const float w11 = fx * fy * det;
            dsum += det;

            const int i0 = yb * WI + xb;
            const int i1 = i0 + WI;
            { const float2 a = *(const float2*)(p0 + i0), c2 = *(const float2*)(p0 + i1);
              acc0 += a.x * w00 + a.y * w01 + c2.x * w10 + c2.y * w11; }
            { const float2 a = *(const float2*)(p1 + i0), c2 = *(const float2*)(p1 + i1);
              acc1 += a.x * w00 + a.y * w01 + c2.x * w10 + c2.y * w11; }
            { const float2 a = *(const float2*)(p2 + i0), c2 = *(const float2*)(p2 + i1);
              acc2 += a.x * w00 + a.y * w01 + c2.x * w10 + c2.y * w11; }
        }
    }

    // ---- Combine spp halves across the lane pair ----
    acc0 += __shfl_xor(acc0, 1);
    acc1 += __shfl_xor(acc1, 1);
    acc2 += __shfl_xor(acc2, 1);
    dsum += __shfl_xor(dsum, 1);

    if (h == 0) {
        const float inv_d = 1.0f / dsum;
        const int pix = sy * SW + sx;
        const size_t ob = (size_t)b * CH * (SH * SW) + pix;
        out[ob]                 = acc0 * inv_d;
        out[ob + (SH * SW)]     = acc1 * inv_d;
        out[ob + 2 * (SH * SW)] = acc2 * inv_d;
    }
}

extern "C" void kernel_launch(void* const* d_in, const int* in_sizes, int n_in,
                              void* d_out, int out_size, void* d_ws, size_t ws_size,
                              hipStream_t stream) {
    const float* img    = (const float*)d_in[0];
    const float* t      = (const float*)d_in[1];
    const float* jitter = (const float*)d_in[2];
    float* out          = (float*)d_out;

    // 4 batches x 16x16 tiles = 1024 blocks, 512 threads (2 per sensor px)
    hipLaunchKernelGGL(foveated_tile, dim3(1024), dim3(NTHR), 0, stream,
                       img, t, jitter, out);
}